// Round 6
// baseline (273.014 us; speedup 1.0000x reference)
//
#include <hip/hip_runtime.h>
#include <math.h>

#define SLOPE 0.01f
#define FC1_BLOCKS 512
#define NB 256         // CSR buckets
#define HBLK 256       // histogram blocks in k_front
#define BCHUNK 2048    // edges per k_bucket block
#define F8SC 512.0f    // fp8 e4m3 scale for X64 activations

// ---------------------------------------------------------------------------
// R19: NB 256 (284us). R21: fp8-e4m3 X64 (263us, absmax 1.19e-7).
// R22 FAILED accuracy (fp8 x4 stages -> 1.67e-6 > 6.96e-7 threshold).
// R23 REGRESSED (272.8us): int8+per-row-scale X32a/b/c. Accuracy fine
//     (1.19e-7) but LINE MODEL: random gather cost = 64B cache lines/edge,
//     not bytes. X32 bf16 is already 1 line/edge; int8 saved no lines and
//     the per-edge scale load ADDED a second random line. All gathers are
//     now at the 1-line/edge floor; sub-line formats are dead ends.
// R24: revert X32a/b/c to bf16 (R21 config) + rework k_fused64_fp8 from
//     QG=16/u32-loads to QG=8/uint2-loads, NPB=32: half the load instrs
//     and addr math (matches proven bf16-kernel shape), phase-2 matmul
//     now uses all 256 threads (was 128 idle), grid N/16 -> N/32.
// ---------------------------------------------------------------------------

static inline int cdiv_l(long a, int b) { return (int)((a + (long)b - 1) / (long)b); }

__device__ __forceinline__ unsigned short f2bf(float f) {   // RNE
    union { float f; unsigned int i; } x; x.f = f;
    unsigned int i = x.i;
    i += 0x7fffu + ((i >> 16) & 1u);
    return (unsigned short)(i >> 16);
}
__device__ __forceinline__ float bf2f(unsigned short u) {
    union { unsigned int i; float f; } x; x.i = ((unsigned int)u) << 16;
    return x.f;
}
__device__ __forceinline__ float4 bf2f4(ushort4 u) {
    return make_float4(bf2f(u.x), bf2f(u.y), bf2f(u.z), bf2f(u.w));
}
__device__ __forceinline__ ushort4 f2bf4(float4 f) {
    return make_ushort4(f2bf(f.x), f2bf(f.y), f2bf(f.z), f2bf(f.w));
}

// fp8 e4m3 (OCP, gfx950 native) pack/unpack: 4 values per u32.
__device__ __forceinline__ float4 fp8x4_to_f4(unsigned int u) {
    auto lo = __builtin_amdgcn_cvt_pk_f32_fp8(u, false);   // bytes 0,1
    auto hi = __builtin_amdgcn_cvt_pk_f32_fp8(u, true);    // bytes 2,3
    return make_float4(lo[0], lo[1], hi[0], hi[1]);
}
__device__ __forceinline__ unsigned int f4_to_fp8x4(float4 v) {
    unsigned int u = 0;
    u = __builtin_amdgcn_cvt_pk_fp8_f32(v.x, v.y, u, false);
    u = __builtin_amdgcn_cvt_pk_fp8_f32(v.z, v.w, u, true);
    return u;
}

// ---- merged front: bucket histogram (bhist) | h0 bf16 | W1 pad ----------
__global__ void k_front(const int* __restrict__ col, int* __restrict__ bhist, int E, int S,
                        const float* __restrict__ x, const float* __restrict__ emb,
                        unsigned short* __restrict__ h0, int N,
                        const float* __restrict__ W1, float* __restrict__ W1p,
                        int h0Blocks) {
    int b = blockIdx.x;
    if (b < HBLK) {
        __shared__ int hist[NB];
        int t = threadIdx.x;
        if (t < NB) hist[t] = 0;
        __syncthreads();
        for (int e = b * 256 + t; e < E; e += HBLK * 256)
            atomicAdd(&hist[col[e] / S], 1);
        __syncthreads();
        if (t < NB) bhist[b * NB + t] = hist[t];
        return;
    }
    b -= HBLK;
    if (b < h0Blocks) {
        int idx = b * 256 + threadIdx.x;      // one thread per 4 h0 elements
        if (idx >= N * 32) return;
        int i = idx >> 5;
        int g = idx & 31;                      // k = 4g .. 4g+3
        const float* xr = x + (long)i * 5;
        int id0 = (int)xr[0], id1 = (int)xr[1];
        const float* e0p = emb + (long)id0 * 62;
        const float* e1p = emb + (long)id1 * 62;
        float v[4];
#pragma unroll
        for (int kk = 0; kk < 4; ++kk) {
            int k = 4 * g + kk;
            float val;
            if (k < 62)       val = e0p[k];
            else if (k < 124) val = e1p[k - 62];
            else if (k < 127) val = xr[2 + (k - 124)];
            else              val = 0.f;
            v[kk] = val;
        }
        *(ushort4*)(h0 + (long)i * 128 + 4 * g) =
            make_ushort4(f2bf(v[0]), f2bf(v[1]), f2bf(v[2]), f2bf(v[3]));
        return;
    }
    b -= h0Blocks;
    {   // W1 pad: 128x64, row 127 = 0
        int idx = b * 256 + threadIdx.x;
        if (idx >= 128 * 64) return;
        int k = idx >> 6;
        W1p[idx] = (k < 127) ? W1[idx] : 0.f;
    }
}

// column-sum bhist (parallel) -> exclusive scan -> gcur (cursors) + gstart (fixed)
__global__ void k_bscan(const int* __restrict__ bhist, int* __restrict__ gcur,
                        int* __restrict__ gstart) {
    __shared__ int sums[4][NB];
    __shared__ int sc[NB];
    int t = threadIdx.x;                    // 0..1023
    int colId = t & (NB - 1), part = t >> 8;
    int s = 0;
    for (int b = part * (HBLK / 4); b < (part + 1) * (HBLK / 4); ++b)
        s += bhist[b * NB + colId];
    sums[part][colId] = s;
    __syncthreads();
    if (t < NB) {
        int v = sums[0][t] + sums[1][t] + sums[2][t] + sums[3][t];
        sc[t] = v;
    }
    __syncthreads();
    int v = (t < NB) ? sc[t] : 0;
    for (int d = 1; d < NB; d <<= 1) {
        int u = (t < NB && t >= d) ? sc[t - d] : 0;
        __syncthreads();
        if (t < NB) sc[t] += u;
        __syncthreads();
    }
    if (t < NB) {
        int excl = sc[t] - v;
        gcur[t] = excl;
        gstart[t] = excl;
        if (t == NB - 1) gstart[NB] = sc[t];   // == E
    }
}

// ---------------- bucket-sort edges ----------------
__global__ void k_bucket(const int* __restrict__ row, const int* __restrict__ col,
                         int* __restrict__ gcur, unsigned int* __restrict__ ebuf,
                         int E, int S) {
    __shared__ int hist[NB], base[NB], lcur[NB];
    int t = threadIdx.x;
    if (t < NB) { hist[t] = 0; lcur[t] = 0; }
    __syncthreads();
    int e0 = blockIdx.x * BCHUNK;
    int e1 = min(e0 + BCHUNK, E);
    for (int e = e0 + t; e < e1; e += blockDim.x)
        atomicAdd(&hist[col[e] / S], 1);
    __syncthreads();
    if (t < NB) base[t] = hist[t] ? atomicAdd(&gcur[t], hist[t]) : 0;
    __syncthreads();
    for (int e = e0 + t; e < e1; e += blockDim.x) {
        int c = col[e], r = row[e];
        int b = c / S;
        int p = base[b] + atomicAdd(&lcur[b], 1);
        ebuf[p] = ((unsigned)c << 16) | (unsigned)r;
    }
}

// ---------------- in-bucket counting sort: off, dinv, srcs in one pass --------------
__global__ void k_sortb(const unsigned int* __restrict__ ebuf,
                        const int* __restrict__ gstart,
                        int* __restrict__ off, float* __restrict__ dinv,
                        unsigned short* __restrict__ srcs, int N, int S, int E) {
    __shared__ int cntl[NB];
    __shared__ int lcur[NB];
    int b = blockIdx.x, t = threadIdx.x;
    int base_node = b * S;
    int nNodes = min(S, N - base_node);
    int start = gstart[b], end = gstart[b + 1];
    if (t < S) cntl[t] = 0;
    __syncthreads();
    for (int e = start + t; e < end; e += blockDim.x)
        atomicAdd(&cntl[(int)(ebuf[e] >> 16) - base_node], 1);
    __syncthreads();
    int myc = (t < S) ? cntl[t] : 0;
    // inclusive Hillis-Steele scan over S entries
    for (int d = 1; d < S; d <<= 1) {
        int u = (t < S && t >= d) ? cntl[t - d] : 0;
        __syncthreads();
        if (t < S) cntl[t] += u;
        __syncthreads();
    }
    if (t < nNodes) {
        int excl = cntl[t] - myc;
        int node = base_node + t;
        off[node] = start + excl;
        dinv[node] = (float)(1.0 / sqrt((double)myc + 1.0));
        lcur[t] = excl;
    }
    if (b == NB - 1 && t == 0) off[N] = E;
    __syncthreads();
    for (int e = start + t; e < end; e += blockDim.x) {
        unsigned p = ebuf[e];
        int cl = (int)(p >> 16) - base_node;
        int pos = start + atomicAdd(&lcur[cl], 1);
        srcs[pos] = (unsigned short)(p & 0xFFFFu);
    }
}

// ---------------- L1 dense: X64 = fp8( (h0 @ W1p) * dinv * F8SC ), 4x4 tiles ------
__global__ void k_hw_rb8(const unsigned short* __restrict__ h, int ld,
                         const float* __restrict__ W,
                         const float* __restrict__ dinv, unsigned char* __restrict__ out,
                         int N) {
    constexpr int DIN = 128, DOUT = 64;
    constexpr int Q = DOUT / 4;
    int tid = blockIdx.x * blockDim.x + threadIdx.x;
    int G = (N + 3) >> 2;
    if (tid >= G * Q) return;
    int g = tid / Q;
    int q = tid % Q;
    int i0 = 4 * g;
    const ushort4* h0 = (const ushort4*)(h + (long)i0 * ld);
    const ushort4* h1 = (const ushort4*)(h + (long)(i0 + 1) * ld);
    const ushort4* h2 = (const ushort4*)(h + (long)(i0 + 2) * ld);
    const ushort4* h3 = (const ushort4*)(h + (long)(i0 + 3) * ld);
    const float* wp = W + 4 * q;
    float4 acc0 = make_float4(0.f, 0.f, 0.f, 0.f);
    float4 acc1 = acc0, acc2 = acc0, acc3 = acc0;
#pragma unroll 4
    for (int kk = 0; kk < DIN / 4; ++kk) {
        float4 a0 = bf2f4(h0[kk]), a1 = bf2f4(h1[kk]);
        float4 a2 = bf2f4(h2[kk]), a3 = bf2f4(h3[kk]);
        float4 w0 = *(const float4*)(wp + (long)(4 * kk)     * DOUT);
        float4 w1 = *(const float4*)(wp + (long)(4 * kk + 1) * DOUT);
        float4 w2 = *(const float4*)(wp + (long)(4 * kk + 2) * DOUT);
        float4 w3 = *(const float4*)(wp + (long)(4 * kk + 3) * DOUT);
        acc0.x += a0.x * w0.x + a0.y * w1.x + a0.z * w2.x + a0.w * w3.x;
        acc0.y += a0.x * w0.y + a0.y * w1.y + a0.z * w2.y + a0.w * w3.y;
        acc0.z += a0.x * w0.z + a0.y * w1.z + a0.z * w2.z + a0.w * w3.z;
        acc0.w += a0.x * w0.w + a0.y * w1.w + a0.z * w2.w + a0.w * w3.w;
        acc1.x += a1.x * w0.x + a1.y * w1.x + a1.z * w2.x + a1.w * w3.x;
        acc1.y += a1.x * w0.y + a1.y * w1.y + a1.z * w2.y + a1.w * w3.y;
        acc1.z += a1.x * w0.z + a1.y * w1.z + a1.z * w2.z + a1.w * w3.z;
        acc1.w += a1.x * w0.w + a1.y * w1.w + a1.z * w2.w + a1.w * w3.w;
        acc2.x += a2.x * w0.x + a2.y * w1.x + a2.z * w2.x + a2.w * w3.x;
        acc2.y += a2.x * w0.y + a2.y * w1.y + a2.z * w2.y + a2.w * w3.y;
        acc2.z += a2.x * w0.z + a2.y * w1.z + a2.z * w2.z + a2.w * w3.z;
        acc2.w += a2.x * w0.w + a2.y * w1.w + a2.z * w2.w + a2.w * w3.w;
        acc3.x += a3.x * w0.x + a3.y * w1.x + a3.z * w2.x + a3.w * w3.x;
        acc3.y += a3.x * w0.y + a3.y * w1.y + a3.z * w2.y + a3.w * w3.y;
        acc3.z += a3.x * w0.z + a3.y * w1.z + a3.z * w2.z + a3.w * w3.z;
        acc3.w += a3.x * w0.w + a3.y * w1.w + a3.z * w2.w + a3.w * w3.w;
    }
    float d0 = dinv[i0] * F8SC, d1 = dinv[i0 + 1] * F8SC;
    float d2 = dinv[i0 + 2] * F8SC, d3 = dinv[i0 + 3] * F8SC;
    acc0.x *= d0; acc0.y *= d0; acc0.z *= d0; acc0.w *= d0;
    acc1.x *= d1; acc1.y *= d1; acc1.z *= d1; acc1.w *= d1;
    acc2.x *= d2; acc2.y *= d2; acc2.z *= d2; acc2.w *= d2;
    acc3.x *= d3; acc3.y *= d3; acc3.z *= d3; acc3.w *= d3;
    unsigned char* op = out + (long)i0 * DOUT + 4 * q;
    *(unsigned int*)(op) = f4_to_fp8x4(acc0);
    if (i0 + 1 < N) *(unsigned int*)(op + DOUT)     = f4_to_fp8x4(acc1);
    if (i0 + 2 < N) *(unsigned int*)(op + 2 * DOUT) = f4_to_fp8x4(acc2);
    if (i0 + 3 < N) *(unsigned int*)(op + 3 * DOUT) = f4_to_fp8x4(acc3);
}

// ---- fused L2: gather fp8 64-dim (uint2/lane) -> lrelu -> matmul W2 -> bf16 -------
// R24: QG=8 (8B loads, half the load instrs of QG=16/u32), NPB=32, phase-2
// uses all 256 threads.
__global__ void k_fused64_fp8(const int* __restrict__ off,
                              const unsigned short* __restrict__ srcs,
                              const float* __restrict__ dinv,
                              const unsigned char* __restrict__ hin,  // fp8, x F8SC
                              const float* __restrict__ bg,
                              const float* __restrict__ W,
                              unsigned short* __restrict__ hwsOut, int N) {
    constexpr int DG = 64, QG = 8, NPB = 32;
    __shared__ float hrow[NPB][DG + 4];
    int t = threadIdx.x;
    int n = t / QG, q = t % QG;            // q covers elements [8q, 8q+8)
    int c = blockIdx.x * NPB + n;
    const uint2* hp = (const uint2*)hin;   // row stride 8 uint2 (64B)
    if (c < N) {
        int e0 = off[c], e1 = off[c + 1];
        float dc = dinv[c] * (1.0f / F8SC);
        uint2 sv = hp[((long)c << 3) + q];  // self
        float4 accA = fp8x4_to_f4(sv.x);
        float4 accB = fp8x4_to_f4(sv.y);
        int e = e0;
        for (; e + 7 < e1; e += 8) {
            int r0 = srcs[e],     r1 = srcs[e + 1], r2 = srcs[e + 2], r3 = srcs[e + 3];
            int r4 = srcs[e + 4], r5 = srcs[e + 5], r6 = srcs[e + 6], r7 = srcs[e + 7];
            uint2 u0 = hp[((long)r0 << 3) + q];
            uint2 u1 = hp[((long)r1 << 3) + q];
            uint2 u2 = hp[((long)r2 << 3) + q];
            uint2 u3 = hp[((long)r3 << 3) + q];
            uint2 u4 = hp[((long)r4 << 3) + q];
            uint2 u5 = hp[((long)r5 << 3) + q];
            uint2 u6 = hp[((long)r6 << 3) + q];
            uint2 u7 = hp[((long)r7 << 3) + q];
            float4 a0 = fp8x4_to_f4(u0.x), b0 = fp8x4_to_f4(u0.y);
            float4 a1 = fp8x4_to_f4(u1.x), b1 = fp8x4_to_f4(u1.y);
            float4 a2 = fp8x4_to_f4(u2.x), b2 = fp8x4_to_f4(u2.y);
            float4 a3 = fp8x4_to_f4(u3.x), b3 = fp8x4_to_f4(u3.y);
            float4 a4 = fp8x4_to_f4(u4.x), b4 = fp8x4_to_f4(u4.y);
            float4 a5 = fp8x4_to_f4(u5.x), b5 = fp8x4_to_f4(u5.y);
            float4 a6 = fp8x4_to_f4(u6.x), b6 = fp8x4_to_f4(u6.y);
            float4 a7 = fp8x4_to_f4(u7.x), b7 = fp8x4_to_f4(u7.y);
            accA.x += (a0.x + a1.x) + (a2.x + a3.x) + (a4.x + a5.x) + (a6.x + a7.x);
            accA.y += (a0.y + a1.y) + (a2.y + a3.y) + (a4.y + a5.y) + (a6.y + a7.y);
            accA.z += (a0.z + a1.z) + (a2.z + a3.z) + (a4.z + a5.z) + (a6.z + a7.z);
            accA.w += (a0.w + a1.w) + (a2.w + a3.w) + (a4.w + a5.w) + (a6.w + a7.w);
            accB.x += (b0.x + b1.x) + (b2.x + b3.x) + (b4.x + b5.x) + (b6.x + b7.x);
            accB.y += (b0.y + b1.y) + (b2.y + b3.y) + (b4.y + b5.y) + (b6.y + b7.y);
            accB.z += (b0.z + b1.z) + (b2.z + b3.z) + (b4.z + b5.z) + (b6.z + b7.z);
            accB.w += (b0.w + b1.w) + (b2.w + b3.w) + (b4.w + b5.w) + (b6.w + b7.w);
        }
        for (; e < e1; ++e) {
            int r = srcs[e];
            uint2 u = hp[((long)r << 3) + q];
            float4 a = fp8x4_to_f4(u.x), b = fp8x4_to_f4(u.y);
            accA.x += a.x; accA.y += a.y; accA.z += a.z; accA.w += a.w;
            accB.x += b.x; accB.y += b.y; accB.z += b.z; accB.w += b.w;
        }
        float4 bbA = *(const float4*)(bg + 8 * q);
        float4 bbB = *(const float4*)(bg + 8 * q + 4);
        float t0 = accA.x * dc + bbA.x, t1 = accA.y * dc + bbA.y;
        float t2 = accA.z * dc + bbA.z, t3 = accA.w * dc + bbA.w;
        float t4 = accB.x * dc + bbB.x, t5 = accB.y * dc + bbB.y;
        float t6 = accB.z * dc + bbB.z, t7 = accB.w * dc + bbB.w;
        float4 rA, rB;   // mode 0: lrelu
        rA.x = (t0 >= 0.f) ? t0 : SLOPE * t0;
        rA.y = (t1 >= 0.f) ? t1 : SLOPE * t1;
        rA.z = (t2 >= 0.f) ? t2 : SLOPE * t2;
        rA.w = (t3 >= 0.f) ? t3 : SLOPE * t3;
        rB.x = (t4 >= 0.f) ? t4 : SLOPE * t4;
        rB.y = (t5 >= 0.f) ? t5 : SLOPE * t5;
        rB.z = (t6 >= 0.f) ? t6 : SLOPE * t6;
        rB.w = (t7 >= 0.f) ? t7 : SLOPE * t7;
        *(float4*)&hrow[n][8 * q]     = rA;
        *(float4*)&hrow[n][8 * q + 4] = rB;
    }
    __syncthreads();
    // phase 2: per-node matmul (64 x 32), 8 threads/node, 4 outputs each -> bf16
    int n2 = t >> 3;
    int q2 = t & 7;
    {
        int c2 = blockIdx.x * NPB + n2;
        if (c2 < N) {
            const float* wp = W + 4 * q2;
            float4 acc = make_float4(0.f, 0.f, 0.f, 0.f);
#pragma unroll
            for (int kk = 0; kk < DG / 4; ++kk) {
                float4 a = *(const float4*)&hrow[n2][4 * kk];
                float4 w0 = *(const float4*)(wp + (long)(4 * kk)     * 32);
                float4 w1 = *(const float4*)(wp + (long)(4 * kk + 1) * 32);
                float4 w2 = *(const float4*)(wp + (long)(4 * kk + 2) * 32);
                float4 w3 = *(const float4*)(wp + (long)(4 * kk + 3) * 32);
                acc.x += a.x * w0.x + a.y * w1.x + a.z * w2.x + a.w * w3.x;
                acc.y += a.x * w0.y + a.y * w1.y + a.z * w2.y + a.w * w3.y;
                acc.z += a.x * w0.z + a.y * w1.z + a.z * w2.z + a.w * w3.z;
                acc.w += a.x * w0.w + a.y * w1.w + a.z * w2.w + a.w * w3.w;
            }
            float di = dinv[c2];
            acc.x *= di; acc.y *= di; acc.z *= di; acc.w *= di;
            *(ushort4*)(hwsOut + (long)c2 * 32 + 4 * q2) = f2bf4(acc);
        }
    }
}

// ---------------- fused: gather layer l (DG-dim bf16) -> act -> matmul W (DG x 32) --
template<int DG>
__global__ void k_fused(const int* __restrict__ off,
                        const unsigned short* __restrict__ srcs,
                        const float* __restrict__ dinv,
                        const unsigned short* __restrict__ hin,
                        const float* __restrict__ bg, int mode,
                        const float* __restrict__ W,
                        unsigned short* __restrict__ hwsOut, int N) {
    constexpr int QG = DG / 4;
    constexpr int NPB = 256 / QG;
    __shared__ float hrow[NPB][DG + 4];
    int t = threadIdx.x;
    int n = t / QG, q = t % QG;
    int c = blockIdx.x * NPB + n;
    if (c < N) {
        int e0 = off[c], e1 = off[c + 1];
        float dc = dinv[c];
        float4 acc = bf2f4(*(const ushort4*)(hin + (long)c * DG + 4 * q));  // self
        int e = e0;
        for (; e + 7 < e1; e += 8) {
            int r0 = srcs[e],     r1 = srcs[e + 1], r2 = srcs[e + 2], r3 = srcs[e + 3];
            int r4 = srcs[e + 4], r5 = srcs[e + 5], r6 = srcs[e + 6], r7 = srcs[e + 7];
            float4 v0 = bf2f4(*(const ushort4*)(hin + (long)r0 * DG + 4 * q));
            float4 v1 = bf2f4(*(const ushort4*)(hin + (long)r1 * DG + 4 * q));
            float4 v2 = bf2f4(*(const ushort4*)(hin + (long)r2 * DG + 4 * q));
            float4 v3 = bf2f4(*(const ushort4*)(hin + (long)r3 * DG + 4 * q));
            float4 v4 = bf2f4(*(const ushort4*)(hin + (long)r4 * DG + 4 * q));
            float4 v5 = bf2f4(*(const ushort4*)(hin + (long)r5 * DG + 4 * q));
            float4 v6 = bf2f4(*(const ushort4*)(hin + (long)r6 * DG + 4 * q));
            float4 v7 = bf2f4(*(const ushort4*)(hin + (long)r7 * DG + 4 * q));
            acc.x += (v0.x + v1.x) + (v2.x + v3.x);
            acc.y += (v0.y + v1.y) + (v2.y + v3.y);
            acc.z += (v0.z + v1.z) + (v2.z + v3.z);
            acc.w += (v0.w + v1.w) + (v2.w + v3.w);
            acc.x += (v4.x + v5.x) + (v6.x + v7.x);
            acc.y += (v4.y + v5.y) + (v6.y + v7.y);
            acc.z += (v4.z + v5.z) + (v6.z + v7.z);
            acc.w += (v4.w + v5.w) + (v6.w + v7.w);
        }
        for (; e + 3 < e1; e += 4) {
            int r0 = srcs[e], r1 = srcs[e + 1], r2 = srcs[e + 2], r3 = srcs[e + 3];
            float4 v0 = bf2f4(*(const ushort4*)(hin + (long)r0 * DG + 4 * q));
            float4 v1 = bf2f4(*(const ushort4*)(hin + (long)r1 * DG + 4 * q));
            float4 v2 = bf2f4(*(const ushort4*)(hin + (long)r2 * DG + 4 * q));
            float4 v3 = bf2f4(*(const ushort4*)(hin + (long)r3 * DG + 4 * q));
            acc.x += (v0.x + v1.x) + (v2.x + v3.x);
            acc.y += (v0.y + v1.y) + (v2.y + v3.y);
            acc.z += (v0.z + v1.z) + (v2.z + v3.z);
            acc.w += (v0.w + v1.w) + (v2.w + v3.w);
        }
        for (; e < e1; ++e) {
            int r = srcs[e];
            float4 v = bf2f4(*(const ushort4*)(hin + (long)r * DG + 4 * q));
            acc.x += v.x; acc.y += v.y; acc.z += v.z; acc.w += v.w;
        }
        float4 bb = *(const float4*)(bg + 4 * q);
        float t0 = acc.x * dc + bb.x, t1 = acc.y * dc + bb.y;
        float t2 = acc.z * dc + bb.z, t3 = acc.w * dc + bb.w;
        float4 res;
        if (mode == 0) {
            res.x = (t0 >= 0.f) ? t0 : SLOPE * t0;
            res.y = (t1 >= 0.f) ? t1 : SLOPE * t1;
            res.z = (t2 >= 0.f) ? t2 : SLOPE * t2;
            res.w = (t3 >= 0.f) ? t3 : SLOPE * t3;
        } else {
            res.x = (t0 >= 0.f) ? 2.f * t0 : (1.f + SLOPE) * t0;
            res.y = (t1 >= 0.f) ? 2.f * t1 : (1.f + SLOPE) * t1;
            res.z = (t2 >= 0.f) ? 2.f * t2 : (1.f + SLOPE) * t2;
            res.w = (t3 >= 0.f) ? 2.f * t3 : (1.f + SLOPE) * t3;
        }
        *(float4*)&hrow[n][4 * q] = res;
    }
    __syncthreads();
    // phase 2: per-node matmul (DG x 32), 8 threads/node, 4 outputs each
    int n2 = t >> 3;
    int q2 = t & 7;
    if (n2 < NPB) {
        int c2 = blockIdx.x * NPB + n2;
        if (c2 < N) {
            const float* wp = W + 4 * q2;
            float4 acc = make_float4(0.f, 0.f, 0.f, 0.f);
#pragma unroll
            for (int kk = 0; kk < DG / 4; ++kk) {
                float4 a = *(const float4*)&hrow[n2][4 * kk];
                float4 w0 = *(const float4*)(wp + (long)(4 * kk)     * 32);
                float4 w1 = *(const float4*)(wp + (long)(4 * kk + 1) * 32);
                float4 w2 = *(const float4*)(wp + (long)(4 * kk + 2) * 32);
                float4 w3 = *(const float4*)(wp + (long)(4 * kk + 3) * 32);
                acc.x += a.x * w0.x + a.y * w1.x + a.z * w2.x + a.w * w3.x;
                acc.y += a.x * w0.y + a.y * w1.y + a.z * w2.y + a.w * w3.y;
                acc.z += a.x * w0.z + a.y * w1.z + a.z * w2.z + a.w * w3.z;
                acc.w += a.x * w0.w + a.y * w1.w + a.z * w2.w + a.w * w3.w;
            }
            float di = dinv[c2];
            acc.x *= di; acc.y *= di; acc.z *= di; acc.w *= di;
            *(ushort4*)(hwsOut + (long)c2 * 32 + 4 * q2) = f2bf4(acc);
        }
    }
}

// fused last: gather (32-dim, mode1) -> act -> dot W5 (32x1) -> f32 hws
__global__ void k_fused_last(const int* __restrict__ off,
                             const unsigned short* __restrict__ srcs,
                             const float* __restrict__ dinv,
                             const unsigned short* __restrict__ hin,
                             const float* __restrict__ bg,
                             const float* __restrict__ W5,
                             float* __restrict__ hwsOut, int N) {
    constexpr int QG = 8;
    constexpr int NPB = 32;
    __shared__ float hrow[NPB][36];
    int t = threadIdx.x;
    int n = t / QG, q = t % QG;
    int c = blockIdx.x * NPB + n;
    if (c < N) {
        int e0 = off[c], e1 = off[c + 1];
        float dc = dinv[c];
        float4 acc = bf2f4(*(const ushort4*)(hin + (long)c * 32 + 4 * q));
        int e = e0;
        for (; e + 7 < e1; e += 8) {
            int r0 = srcs[e],     r1 = srcs[e + 1], r2 = srcs[e + 2], r3 = srcs[e + 3];
            int r4 = srcs[e + 4], r5 = srcs[e + 5], r6 = srcs[e + 6], r7 = srcs[e + 7];
            float4 v0 = bf2f4(*(const ushort4*)(hin + (long)r0 * 32 + 4 * q));
            float4 v1 = bf2f4(*(const ushort4*)(hin + (long)r1 * 32 + 4 * q));
            float4 v2 = bf2f4(*(const ushort4*)(hin + (long)r2 * 32 + 4 * q));
            float4 v3 = bf2f4(*(const ushort4*)(hin + (long)r3 * 32 + 4 * q));
            float4 v4 = bf2f4(*(const ushort4*)(hin + (long)r4 * 32 + 4 * q));
            float4 v5 = bf2f4(*(const ushort4*)(hin + (long)r5 * 32 + 4 * q));
            float4 v6 = bf2f4(*(const ushort4*)(hin + (long)r6 * 32 + 4 * q));
            float4 v7 = bf2f4(*(const ushort4*)(hin + (long)r7 * 32 + 4 * q));
            acc.x += (v0.x + v1.x) + (v2.x + v3.x);
            acc.y += (v0.y + v1.y) + (v2.y + v3.y);
            acc.z += (v0.z + v1.z) + (v2.z + v3.z);
            acc.w += (v0.w + v1.w) + (v2.w + v3.w);
            acc.x += (v4.x + v5.x) + (v6.x + v7.x);
            acc.y += (v4.y + v5.y) + (v6.y + v7.y);
            acc.z += (v4.z + v5.z) + (v6.z + v7.z);
            acc.w += (v4.w + v5.w) + (v6.w + v7.w);
        }
        for (; e + 3 < e1; e += 4) {
            int r0 = srcs[e], r1 = srcs[e + 1], r2 = srcs[e + 2], r3 = srcs[e + 3];
            float4 v0 = bf2f4(*(const ushort4*)(hin + (long)r0 * 32 + 4 * q));
            float4 v1 = bf2f4(*(const ushort4*)(hin + (long)r1 * 32 + 4 * q));
            float4 v2 = bf2f4(*(const ushort4*)(hin + (long)r2 * 32 + 4 * q));
            float4 v3 = bf2f4(*(const ushort4*)(hin + (long)r3 * 32 + 4 * q));
            acc.x += (v0.x + v1.x) + (v2.x + v3.x);
            acc.y += (v0.y + v1.y) + (v2.y + v3.y);
            acc.z += (v0.z + v1.z) + (v2.z + v3.z);
            acc.w += (v0.w + v1.w) + (v2.w + v3.w);
        }
        for (; e < e1; ++e) {
            int r = srcs[e];
            float4 v = bf2f4(*(const ushort4*)(hin + (long)r * 32 + 4 * q));
            acc.x += v.x; acc.y += v.y; acc.z += v.z; acc.w += v.w;
        }
        float4 bb = *(const float4*)(bg + 4 * q);
        float t0 = acc.x * dc + bb.x, t1 = acc.y * dc + bb.y;
        float t2 = acc.z * dc + bb.z, t3 = acc.w * dc + bb.w;
        float4 res;   // mode 1
        res.x = (t0 >= 0.f) ? 2.f * t0 : (1.f + SLOPE) * t0;
        res.y = (t1 >= 0.f) ? 2.f * t1 : (1.f + SLOPE) * t1;
        res.z = (t2 >= 0.f) ? 2.f * t2 : (1.f + SLOPE) * t2;
        res.w = (t3 >= 0.f) ? 2.f * t3 : (1.f + SLOPE) * t3;
        *(float4*)&hrow[n][4 * q] = res;
    }
    __syncthreads();
    if (t < NPB) {
        int c2 = blockIdx.x * NPB + t;
        if (c2 < N) {
            float acc = 0.f;
#pragma unroll
            for (int kk = 0; kk < 8; ++kk) {
                float4 a = *(const float4*)&hrow[t][4 * kk];
                acc += a.x * W5[4 * kk] + a.y * W5[4 * kk + 1]
                     + a.z * W5[4 * kk + 2] + a.w * W5[4 * kk + 3];
            }
            hwsOut[c2] = acc * dinv[c2];
        }
    }
}

// ---------------- tail: final gather (V in LDS) + fc1a partials fused ---------------
__global__ void k_tail(const int* __restrict__ off,
                       const unsigned short* __restrict__ srcs,
                       const float* __restrict__ dinv, const float* __restrict__ hws,
                       const float* __restrict__ b5,
                       const float* __restrict__ Wf1, double* __restrict__ part,
                       int N, int chunk) {
    __shared__ float Vl[96];
    int bl = blockIdx.x, t = threadIdx.x;
    int i0 = bl * chunk;
    int i1 = min(i0 + chunk, N);
    int cnt = i1 - i0;
    if (t < cnt) {
        int c = i0 + t;
        int e0 = off[c], e1 = off[c + 1];
        float acc = hws[c];
        float a1 = 0.f, a2 = 0.f, a3 = 0.f;
        int e = e0;
        for (; e + 3 < e1; e += 4) {
            acc += hws[srcs[e]];
            a1  += hws[srcs[e + 1]];
            a2  += hws[srcs[e + 2]];
            a3  += hws[srcs[e + 3]];
        }
        for (; e < e1; ++e) acc += hws[srcs[e]];
        float tt = (acc + a1 + a2 + a3) * dinv[c] + b5[0];
        Vl[t] = (tt >= 0.f) ? tt : SLOPE * tt;
    }
    __syncthreads();
    int j = t;   // 128 threads, one per output column
    double a0 = 0.0, a1 = 0.0, a2 = 0.0, a3 = 0.0;
    int i = 0;
    for (; i + 3 < cnt; i += 4) {
        a0 += (double)Vl[i]     * (double)Wf1[(long)(i0 + i)     * 128 + j];
        a1 += (double)Vl[i + 1] * (double)Wf1[(long)(i0 + i + 1) * 128 + j];
        a2 += (double)Vl[i + 2] * (double)Wf1[(long)(i0 + i + 2) * 128 + j];
        a3 += (double)Vl[i + 3] * (double)Wf1[(long)(i0 + i + 3) * 128 + j];
    }
    for (; i < cnt; ++i)
        a0 += (double)Vl[i] * (double)Wf1[(long)(i0 + i) * 128 + j];
    part[bl * 128 + j] = (a0 + a1) + (a2 + a3);
}

__global__ void k_fc1b(const double* __restrict__ part, const float* __restrict__ bf1,
                       float* __restrict__ o1) {
    __shared__ double red[256];
    int j = blockIdx.x;
    int t = threadIdx.x;
    double a = part[t * 128 + j] + part[(t + 256) * 128 + j];
    red[t] = a;
    __syncthreads();
    for (int s = 128; s > 0; s >>= 1) {
        if (t < s) red[t] += red[t + s];
        __syncthreads();
    }
    if (t == 0) {
        double v = red[0] + (double)bf1[j];
        o1[j] = (float)((v > 0.0) ? v : 0.0);
    }
}

__global__ void k_fc2(const float* __restrict__ o1, const float* __restrict__ Wf2,
                      const float* __restrict__ bf2, float* __restrict__ out) {
    __shared__ double red[128];
    int j = blockIdx.x;
    int k = threadIdx.x;
    red[k] = (double)o1[k] * (double)Wf2[(long)k * 128 + j];
    __syncthreads();
    for (int s = 64; s > 0; s >>= 1) {
        if (k < s) red[k] += red[k + s];
        __syncthreads();
    }
    if (k == 0) {
        double u = red[0] + (double)bf2[j];
        out[j] = (float)((u > 0.0) ? u : 0.0);
    }
}

extern "C" void kernel_launch(void* const* d_in, const int* in_sizes, int n_in,
                              void* d_out, int out_size, void* d_ws, size_t ws_size,
                              hipStream_t stream) {
    const float* x   = (const float*)d_in[0];
    const int*   ei  = (const int*)d_in[1];
    const float* emb = (const float*)d_in[2];
    const float* W1  = (const float*)d_in[3];
    const float* b1  = (const float*)d_in[4];
    const float* W2  = (const float*)d_in[5];
    const float* b2  = (const float*)d_in[6];
    const float* W3  = (const float*)d_in[7];
    const float* b3  = (const float*)d_in[8];
    const float* W4  = (const float*)d_in[9];
    const float* b4  = (const float*)d_in[10];
    const float* W5  = (const float*)d_in[11];
    const float* b5  = (const float*)d_in[12];
    const float* Wf1 = (const float*)d_in[13];
    const float* bf1 = (const float*)d_in[14];
    const float* Wf2 = (const float*)d_in[15];
    const float* bf2 = (const float*)d_in[16];

    const int N = in_sizes[0] / 5;
    const int E = in_sizes[1] / 2;
    const int* row = ei;
    const int* col = ei + E;
    const int S = (N + NB - 1) / NB;           // bucket width (150 for N=38333, NB=256)
    const int Np = N + 4;                       // padded rows for 4-node tiles

    // --- workspace carving ---
    char* ws = (char*)d_ws;
    size_t off_b = 0;
    auto alloc = [&](size_t bytes) -> void* {
        void* p = ws + off_b;
        off_b += (bytes + 255) & ~(size_t)255;
        return p;
    };
    int*   offcsr = (int*)alloc((size_t)(N + 1) * sizeof(int));
    int*   bhist  = (int*)alloc((size_t)HBLK * NB * sizeof(int));
    int*   gcur   = (int*)alloc((size_t)NB * sizeof(int));
    int*   gstart = (int*)alloc((size_t)(NB + 1) * sizeof(int));
    unsigned short* srcs = (unsigned short*)alloc((size_t)E * sizeof(unsigned short));
    unsigned int* ebuf = (unsigned int*)alloc((size_t)E * sizeof(unsigned int));
    float* dinv   = (float*)alloc((size_t)Np * sizeof(float));
    float* W1p    = (float*)alloc((size_t)128 * 64 * sizeof(float));
    unsigned short* H0   = (unsigned short*)alloc((size_t)Np * 128 * sizeof(unsigned short));
    unsigned char*  X64f8 = (unsigned char*)alloc((size_t)Np * 64 * sizeof(unsigned char));
    unsigned short* X32a = (unsigned short*)alloc((size_t)Np * 32 * sizeof(unsigned short));
    unsigned short* X32b = (unsigned short*)alloc((size_t)Np * 32 * sizeof(unsigned short));
    unsigned short* X32c = (unsigned short*)alloc((size_t)Np * 32 * sizeof(unsigned short));
    float* HWSf   = (float*)alloc((size_t)Np * sizeof(float));
    double* part  = (double*)alloc((size_t)FC1_BLOCKS * 128 * sizeof(double));
    float* O1     = (float*)alloc(128 * sizeof(float));

    // --- front: merged (bucket-hist -> bhist | h0 bf16 x4 | W1pad) ---
    int h0Blocks  = cdiv_l((long)N * 32, 256);
    int padBlocks = cdiv_l(128 * 64, 256);
    k_front<<<HBLK + h0Blocks + padBlocks, 256, 0, stream>>>(
        col, bhist, E, S, x, emb, H0, N, W1, W1p, h0Blocks);

    // --- CSR build: bscan -> bucket -> in-bucket counting sort ---
    k_bscan<<<1, 1024, 0, stream>>>(bhist, gcur, gstart);
    k_bucket<<<cdiv_l(E, BCHUNK), 256, 0, stream>>>(row, col, gcur, ebuf, E, S);
    k_sortb<<<NB, 1024, 0, stream>>>(ebuf, gstart, offcsr, dinv, srcs, N, S, E);

    // --- GCN: L1 dense (fp8 out), then fused gather+matmul chain ---
    {
        int G = (N + 3) / 4;
        k_hw_rb8<<<cdiv_l((long)G * 16, 256), 256, 0, stream>>>(
            H0, 128, W1p, dinv, X64f8, N);
    }
    k_fused64_fp8<<<cdiv_l(N, 32), 256, 0, stream>>>(
        offcsr, srcs, dinv, X64f8, b1, W2, X32a, N);
    k_fused<32><<<cdiv_l(N, 32), 256, 0, stream>>>(
        offcsr, srcs, dinv, X32a, b2, 0, W3, X32b, N);
    k_fused<32><<<cdiv_l(N, 32), 256, 0, stream>>>(
        offcsr, srcs, dinv, X32b, b3, 1, W4, X32c, N);
    k_fused_last<<<cdiv_l(N, 32), 256, 0, stream>>>(
        offcsr, srcs, dinv, X32c, b4, W5, HWSf, N);

    // --- tail: final gather + fc1a fused; then fc1b, fc2 ---
    int chunk = (N + FC1_BLOCKS - 1) / FC1_BLOCKS;   // 75 (< 96 LDS cap)
    k_tail<<<FC1_BLOCKS, 128, 0, stream>>>(
        offcsr, srcs, dinv, HWSf, b5, Wf1, part, N, chunk);
    k_fc1b<<<128, 256, 0, stream>>>(part, bf1, O1);
    k_fc2<<<128, 128, 0, stream>>>(O1, Wf2, bf2, (float*)d_out);
}

// Round 7
// 262.352 us; speedup vs baseline: 1.0406x; 1.0406x over previous
//
#include <hip/hip_runtime.h>
#include <math.h>

#define SLOPE 0.01f
#define FC1_BLOCKS 512
#define NB 256         // CSR buckets
#define HBLK 256       // histogram blocks in k_front
#define BCHUNK 2048    // edges per k_bucket block
#define F8SC 512.0f    // fp8 e4m3 scale for X64 activations

// ---------------------------------------------------------------------------
// R19: NB 256 (284us). R21: fp8-e4m3 X64 (263us, absmax 1.19e-7).
// R22 FAILED accuracy (4x fp8 stages). R23 REGRESSED (line model: gather
//     cost = lines/edge; sub-line formats dead). 
// R24 (273us): X32 bf16 revert was right, but fused64 QG=16->8 halved
//     thread count and COST ~10us at identical line traffic =>
//     gathers are CONCURRENCY-bound, not request-rate-bound.
// R25: (a) fused64 back to exact R21 shape (QG=16/u32/NPB=16, grid N/16);
//     (b) apply the lesson to the three 32-dim gather kernels: QG=8/NPB=32
//     (1198 blocks, every round so far) -> QG=16/NPB=16 (2396 blocks,
//     u32 = 2 bf16 per thread). 2x threads, 2x outstanding loads, same
//     lines. Phase-2 matmuls unchanged.
// ---------------------------------------------------------------------------

static inline int cdiv_l(long a, int b) { return (int)((a + (long)b - 1) / (long)b); }

__device__ __forceinline__ unsigned short f2bf(float f) {   // RNE
    union { float f; unsigned int i; } x; x.f = f;
    unsigned int i = x.i;
    i += 0x7fffu + ((i >> 16) & 1u);
    return (unsigned short)(i >> 16);
}
__device__ __forceinline__ float bf2f(unsigned short u) {
    union { unsigned int i; float f; } x; x.i = ((unsigned int)u) << 16;
    return x.f;
}
__device__ __forceinline__ float4 bf2f4(ushort4 u) {
    return make_float4(bf2f(u.x), bf2f(u.y), bf2f(u.z), bf2f(u.w));
}
__device__ __forceinline__ ushort4 f2bf4(float4 f) {
    return make_ushort4(f2bf(f.x), f2bf(f.y), f2bf(f.z), f2bf(f.w));
}
// 2 bf16 packed in a u32 (little-endian: low half = even element)
__device__ __forceinline__ float2 bfp2_to_f2(unsigned int u) {
    return make_float2(bf2f((unsigned short)(u & 0xffffu)),
                       bf2f((unsigned short)(u >> 16)));
}

// fp8 e4m3 (OCP, gfx950 native) pack/unpack: 4 values per u32.
__device__ __forceinline__ float4 fp8x4_to_f4(unsigned int u) {
    auto lo = __builtin_amdgcn_cvt_pk_f32_fp8(u, false);   // bytes 0,1
    auto hi = __builtin_amdgcn_cvt_pk_f32_fp8(u, true);    // bytes 2,3
    return make_float4(lo[0], lo[1], hi[0], hi[1]);
}
__device__ __forceinline__ unsigned int f4_to_fp8x4(float4 v) {
    unsigned int u = 0;
    u = __builtin_amdgcn_cvt_pk_fp8_f32(v.x, v.y, u, false);
    u = __builtin_amdgcn_cvt_pk_fp8_f32(v.z, v.w, u, true);
    return u;
}

// ---- merged front: bucket histogram (bhist) | h0 bf16 | W1 pad ----------
__global__ void k_front(const int* __restrict__ col, int* __restrict__ bhist, int E, int S,
                        const float* __restrict__ x, const float* __restrict__ emb,
                        unsigned short* __restrict__ h0, int N,
                        const float* __restrict__ W1, float* __restrict__ W1p,
                        int h0Blocks) {
    int b = blockIdx.x;
    if (b < HBLK) {
        __shared__ int hist[NB];
        int t = threadIdx.x;
        if (t < NB) hist[t] = 0;
        __syncthreads();
        for (int e = b * 256 + t; e < E; e += HBLK * 256)
            atomicAdd(&hist[col[e] / S], 1);
        __syncthreads();
        if (t < NB) bhist[b * NB + t] = hist[t];
        return;
    }
    b -= HBLK;
    if (b < h0Blocks) {
        int idx = b * 256 + threadIdx.x;      // one thread per 4 h0 elements
        if (idx >= N * 32) return;
        int i = idx >> 5;
        int g = idx & 31;                      // k = 4g .. 4g+3
        const float* xr = x + (long)i * 5;
        int id0 = (int)xr[0], id1 = (int)xr[1];
        const float* e0p = emb + (long)id0 * 62;
        const float* e1p = emb + (long)id1 * 62;
        float v[4];
#pragma unroll
        for (int kk = 0; kk < 4; ++kk) {
            int k = 4 * g + kk;
            float val;
            if (k < 62)       val = e0p[k];
            else if (k < 124) val = e1p[k - 62];
            else if (k < 127) val = xr[2 + (k - 124)];
            else              val = 0.f;
            v[kk] = val;
        }
        *(ushort4*)(h0 + (long)i * 128 + 4 * g) =
            make_ushort4(f2bf(v[0]), f2bf(v[1]), f2bf(v[2]), f2bf(v[3]));
        return;
    }
    b -= h0Blocks;
    {   // W1 pad: 128x64, row 127 = 0
        int idx = b * 256 + threadIdx.x;
        if (idx >= 128 * 64) return;
        int k = idx >> 6;
        W1p[idx] = (k < 127) ? W1[idx] : 0.f;
    }
}

// column-sum bhist (parallel) -> exclusive scan -> gcur (cursors) + gstart (fixed)
__global__ void k_bscan(const int* __restrict__ bhist, int* __restrict__ gcur,
                        int* __restrict__ gstart) {
    __shared__ int sums[4][NB];
    __shared__ int sc[NB];
    int t = threadIdx.x;                    // 0..1023
    int colId = t & (NB - 1), part = t >> 8;
    int s = 0;
    for (int b = part * (HBLK / 4); b < (part + 1) * (HBLK / 4); ++b)
        s += bhist[b * NB + colId];
    sums[part][colId] = s;
    __syncthreads();
    if (t < NB) {
        int v = sums[0][t] + sums[1][t] + sums[2][t] + sums[3][t];
        sc[t] = v;
    }
    __syncthreads();
    int v = (t < NB) ? sc[t] : 0;
    for (int d = 1; d < NB; d <<= 1) {
        int u = (t < NB && t >= d) ? sc[t - d] : 0;
        __syncthreads();
        if (t < NB) sc[t] += u;
        __syncthreads();
    }
    if (t < NB) {
        int excl = sc[t] - v;
        gcur[t] = excl;
        gstart[t] = excl;
        if (t == NB - 1) gstart[NB] = sc[t];   // == E
    }
}

// ---------------- bucket-sort edges ----------------
__global__ void k_bucket(const int* __restrict__ row, const int* __restrict__ col,
                         int* __restrict__ gcur, unsigned int* __restrict__ ebuf,
                         int E, int S) {
    __shared__ int hist[NB], base[NB], lcur[NB];
    int t = threadIdx.x;
    if (t < NB) { hist[t] = 0; lcur[t] = 0; }
    __syncthreads();
    int e0 = blockIdx.x * BCHUNK;
    int e1 = min(e0 + BCHUNK, E);
    for (int e = e0 + t; e < e1; e += blockDim.x)
        atomicAdd(&hist[col[e] / S], 1);
    __syncthreads();
    if (t < NB) base[t] = hist[t] ? atomicAdd(&gcur[t], hist[t]) : 0;
    __syncthreads();
    for (int e = e0 + t; e < e1; e += blockDim.x) {
        int c = col[e], r = row[e];
        int b = c / S;
        int p = base[b] + atomicAdd(&lcur[b], 1);
        ebuf[p] = ((unsigned)c << 16) | (unsigned)r;
    }
}

// ---------------- in-bucket counting sort: off, dinv, srcs in one pass --------------
__global__ void k_sortb(const unsigned int* __restrict__ ebuf,
                        const int* __restrict__ gstart,
                        int* __restrict__ off, float* __restrict__ dinv,
                        unsigned short* __restrict__ srcs, int N, int S, int E) {
    __shared__ int cntl[NB];
    __shared__ int lcur[NB];
    int b = blockIdx.x, t = threadIdx.x;
    int base_node = b * S;
    int nNodes = min(S, N - base_node);
    int start = gstart[b], end = gstart[b + 1];
    if (t < S) cntl[t] = 0;
    __syncthreads();
    for (int e = start + t; e < end; e += blockDim.x)
        atomicAdd(&cntl[(int)(ebuf[e] >> 16) - base_node], 1);
    __syncthreads();
    int myc = (t < S) ? cntl[t] : 0;
    // inclusive Hillis-Steele scan over S entries
    for (int d = 1; d < S; d <<= 1) {
        int u = (t < S && t >= d) ? cntl[t - d] : 0;
        __syncthreads();
        if (t < S) cntl[t] += u;
        __syncthreads();
    }
    if (t < nNodes) {
        int excl = cntl[t] - myc;
        int node = base_node + t;
        off[node] = start + excl;
        dinv[node] = (float)(1.0 / sqrt((double)myc + 1.0));
        lcur[t] = excl;
    }
    if (b == NB - 1 && t == 0) off[N] = E;
    __syncthreads();
    for (int e = start + t; e < end; e += blockDim.x) {
        unsigned p = ebuf[e];
        int cl = (int)(p >> 16) - base_node;
        int pos = start + atomicAdd(&lcur[cl], 1);
        srcs[pos] = (unsigned short)(p & 0xFFFFu);
    }
}

// ---------------- L1 dense: X64 = fp8( (h0 @ W1p) * dinv * F8SC ), 4x4 tiles ------
__global__ void k_hw_rb8(const unsigned short* __restrict__ h, int ld,
                         const float* __restrict__ W,
                         const float* __restrict__ dinv, unsigned char* __restrict__ out,
                         int N) {
    constexpr int DIN = 128, DOUT = 64;
    constexpr int Q = DOUT / 4;
    int tid = blockIdx.x * blockDim.x + threadIdx.x;
    int G = (N + 3) >> 2;
    if (tid >= G * Q) return;
    int g = tid / Q;
    int q = tid % Q;
    int i0 = 4 * g;
    const ushort4* h0 = (const ushort4*)(h + (long)i0 * ld);
    const ushort4* h1 = (const ushort4*)(h + (long)(i0 + 1) * ld);
    const ushort4* h2 = (const ushort4*)(h + (long)(i0 + 2) * ld);
    const ushort4* h3 = (const ushort4*)(h + (long)(i0 + 3) * ld);
    const float* wp = W + 4 * q;
    float4 acc0 = make_float4(0.f, 0.f, 0.f, 0.f);
    float4 acc1 = acc0, acc2 = acc0, acc3 = acc0;
#pragma unroll 4
    for (int kk = 0; kk < DIN / 4; ++kk) {
        float4 a0 = bf2f4(h0[kk]), a1 = bf2f4(h1[kk]);
        float4 a2 = bf2f4(h2[kk]), a3 = bf2f4(h3[kk]);
        float4 w0 = *(const float4*)(wp + (long)(4 * kk)     * DOUT);
        float4 w1 = *(const float4*)(wp + (long)(4 * kk + 1) * DOUT);
        float4 w2 = *(const float4*)(wp + (long)(4 * kk + 2) * DOUT);
        float4 w3 = *(const float4*)(wp + (long)(4 * kk + 3) * DOUT);
        acc0.x += a0.x * w0.x + a0.y * w1.x + a0.z * w2.x + a0.w * w3.x;
        acc0.y += a0.x * w0.y + a0.y * w1.y + a0.z * w2.y + a0.w * w3.y;
        acc0.z += a0.x * w0.z + a0.y * w1.z + a0.z * w2.z + a0.w * w3.z;
        acc0.w += a0.x * w0.w + a0.y * w1.w + a0.z * w2.w + a0.w * w3.w;
        acc1.x += a1.x * w0.x + a1.y * w1.x + a1.z * w2.x + a1.w * w3.x;
        acc1.y += a1.x * w0.y + a1.y * w1.y + a1.z * w2.y + a1.w * w3.y;
        acc1.z += a1.x * w0.z + a1.y * w1.z + a1.z * w2.z + a1.w * w3.z;
        acc1.w += a1.x * w0.w + a1.y * w1.w + a1.z * w2.w + a1.w * w3.w;
        acc2.x += a2.x * w0.x + a2.y * w1.x + a2.z * w2.x + a2.w * w3.x;
        acc2.y += a2.x * w0.y + a2.y * w1.y + a2.z * w2.y + a2.w * w3.y;
        acc2.z += a2.x * w0.z + a2.y * w1.z + a2.z * w2.z + a2.w * w3.z;
        acc2.w += a2.x * w0.w + a2.y * w1.w + a2.z * w2.w + a2.w * w3.w;
        acc3.x += a3.x * w0.x + a3.y * w1.x + a3.z * w2.x + a3.w * w3.x;
        acc3.y += a3.x * w0.y + a3.y * w1.y + a3.z * w2.y + a3.w * w3.y;
        acc3.z += a3.x * w0.z + a3.y * w1.z + a3.z * w2.z + a3.w * w3.z;
        acc3.w += a3.x * w0.w + a3.y * w1.w + a3.z * w2.w + a3.w * w3.w;
    }
    float d0 = dinv[i0] * F8SC, d1 = dinv[i0 + 1] * F8SC;
    float d2 = dinv[i0 + 2] * F8SC, d3 = dinv[i0 + 3] * F8SC;
    acc0.x *= d0; acc0.y *= d0; acc0.z *= d0; acc0.w *= d0;
    acc1.x *= d1; acc1.y *= d1; acc1.z *= d1; acc1.w *= d1;
    acc2.x *= d2; acc2.y *= d2; acc2.z *= d2; acc2.w *= d2;
    acc3.x *= d3; acc3.y *= d3; acc3.z *= d3; acc3.w *= d3;
    unsigned char* op = out + (long)i0 * DOUT + 4 * q;
    *(unsigned int*)(op) = f4_to_fp8x4(acc0);
    if (i0 + 1 < N) *(unsigned int*)(op + DOUT)     = f4_to_fp8x4(acc1);
    if (i0 + 2 < N) *(unsigned int*)(op + 2 * DOUT) = f4_to_fp8x4(acc2);
    if (i0 + 3 < N) *(unsigned int*)(op + 3 * DOUT) = f4_to_fp8x4(acc3);
}

// ---- fused L2 (R21 exact): gather fp8 64-dim (u32/lane, QG=16) -> lrelu ->
//      matmul W2 (64x32) -> bf16 X32a
__global__ void k_fused64_fp8(const int* __restrict__ off,
                              const unsigned short* __restrict__ srcs,
                              const float* __restrict__ dinv,
                              const unsigned char* __restrict__ hin,  // fp8, x F8SC
                              const float* __restrict__ bg,
                              const float* __restrict__ W,
                              unsigned short* __restrict__ hwsOut, int N) {
    constexpr int DG = 64, QG = 16, NPB = 16;
    __shared__ float hrow[NPB][DG + 4];
    int t = threadIdx.x;
    int n = t / QG, q = t % QG;
    int c = blockIdx.x * NPB + n;
    const unsigned int* hp = (const unsigned int*)hin;   // row stride 16 u32
    if (c < N) {
        int e0 = off[c], e1 = off[c + 1];
        float dc = dinv[c] * (1.0f / F8SC);
        float4 acc = fp8x4_to_f4(hp[((long)c << 4) + q]);   // self
        int e = e0;
        for (; e + 7 < e1; e += 8) {
            int r0 = srcs[e],     r1 = srcs[e + 1], r2 = srcs[e + 2], r3 = srcs[e + 3];
            int r4 = srcs[e + 4], r5 = srcs[e + 5], r6 = srcs[e + 6], r7 = srcs[e + 7];
            float4 v0 = fp8x4_to_f4(hp[((long)r0 << 4) + q]);
            float4 v1 = fp8x4_to_f4(hp[((long)r1 << 4) + q]);
            float4 v2 = fp8x4_to_f4(hp[((long)r2 << 4) + q]);
            float4 v3 = fp8x4_to_f4(hp[((long)r3 << 4) + q]);
            float4 v4 = fp8x4_to_f4(hp[((long)r4 << 4) + q]);
            float4 v5 = fp8x4_to_f4(hp[((long)r5 << 4) + q]);
            float4 v6 = fp8x4_to_f4(hp[((long)r6 << 4) + q]);
            float4 v7 = fp8x4_to_f4(hp[((long)r7 << 4) + q]);
            acc.x += (v0.x + v1.x) + (v2.x + v3.x);
            acc.y += (v0.y + v1.y) + (v2.y + v3.y);
            acc.z += (v0.z + v1.z) + (v2.z + v3.z);
            acc.w += (v0.w + v1.w) + (v2.w + v3.w);
            acc.x += (v4.x + v5.x) + (v6.x + v7.x);
            acc.y += (v4.y + v5.y) + (v6.y + v7.y);
            acc.z += (v4.z + v5.z) + (v6.z + v7.z);
            acc.w += (v4.w + v5.w) + (v6.w + v7.w);
        }
        for (; e + 3 < e1; e += 4) {
            int r0 = srcs[e], r1 = srcs[e + 1], r2 = srcs[e + 2], r3 = srcs[e + 3];
            float4 v0 = fp8x4_to_f4(hp[((long)r0 << 4) + q]);
            float4 v1 = fp8x4_to_f4(hp[((long)r1 << 4) + q]);
            float4 v2 = fp8x4_to_f4(hp[((long)r2 << 4) + q]);
            float4 v3 = fp8x4_to_f4(hp[((long)r3 << 4) + q]);
            acc.x += (v0.x + v1.x) + (v2.x + v3.x);
            acc.y += (v0.y + v1.y) + (v2.y + v3.y);
            acc.z += (v0.z + v1.z) + (v2.z + v3.z);
            acc.w += (v0.w + v1.w) + (v2.w + v3.w);
        }
        for (; e < e1; ++e) {
            int r = srcs[e];
            float4 v = fp8x4_to_f4(hp[((long)r << 4) + q]);
            acc.x += v.x; acc.y += v.y; acc.z += v.z; acc.w += v.w;
        }
        float4 bb = *(const float4*)(bg + 4 * q);
        float t0 = acc.x * dc + bb.x, t1 = acc.y * dc + bb.y;
        float t2 = acc.z * dc + bb.z, t3 = acc.w * dc + bb.w;
        float4 res;   // mode 0: lrelu
        res.x = (t0 >= 0.f) ? t0 : SLOPE * t0;
        res.y = (t1 >= 0.f) ? t1 : SLOPE * t1;
        res.z = (t2 >= 0.f) ? t2 : SLOPE * t2;
        res.w = (t3 >= 0.f) ? t3 : SLOPE * t3;
        *(float4*)&hrow[n][4 * q] = res;
    }
    __syncthreads();
    // phase 2: per-node matmul (64 x 32), 8 threads/node, 4 outputs each
    int n2 = t >> 3;
    int q2 = t & 7;
    if (n2 < NPB) {
        int c2 = blockIdx.x * NPB + n2;
        if (c2 < N) {
            const float* wp = W + 4 * q2;
            float4 acc = make_float4(0.f, 0.f, 0.f, 0.f);
#pragma unroll
            for (int kk = 0; kk < DG / 4; ++kk) {
                float4 a = *(const float4*)&hrow[n2][4 * kk];
                float4 w0 = *(const float4*)(wp + (long)(4 * kk)     * 32);
                float4 w1 = *(const float4*)(wp + (long)(4 * kk + 1) * 32);
                float4 w2 = *(const float4*)(wp + (long)(4 * kk + 2) * 32);
                float4 w3 = *(const float4*)(wp + (long)(4 * kk + 3) * 32);
                acc.x += a.x * w0.x + a.y * w1.x + a.z * w2.x + a.w * w3.x;
                acc.y += a.x * w0.y + a.y * w1.y + a.z * w2.y + a.w * w3.y;
                acc.z += a.x * w0.z + a.y * w1.z + a.z * w2.z + a.w * w3.z;
                acc.w += a.x * w0.w + a.y * w1.w + a.z * w2.w + a.w * w3.w;
            }
            float di = dinv[c2];
            acc.x *= di; acc.y *= di; acc.z *= di; acc.w *= di;
            *(ushort4*)(hwsOut + (long)c2 * 32 + 4 * q2) = f2bf4(acc);
        }
    }
}

// ---- fused mid (R25): gather bf16 32-dim, QG=16 (u32 = 2 bf16/thread),
//      NPB=16, grid N/16 -- 2x threads vs old QG=8 for 2x outstanding loads.
__global__ void k_fused32w(const int* __restrict__ off,
                           const unsigned short* __restrict__ srcs,
                           const float* __restrict__ dinv,
                           const unsigned short* __restrict__ hin,
                           const float* __restrict__ bg, int mode,
                           const float* __restrict__ W,
                           unsigned short* __restrict__ hwsOut, int N) {
    constexpr int DG = 32, QG = 16, NPB = 16;
    __shared__ float hrow[NPB][DG + 4];
    int t = threadIdx.x;
    int n = t / QG, q = t % QG;            // q covers elements 2q, 2q+1
    int c = blockIdx.x * NPB + n;
    const unsigned int* hp = (const unsigned int*)hin;   // row stride 16 u32
    if (c < N) {
        int e0 = off[c], e1 = off[c + 1];
        float dc = dinv[c];
        float2 acc = bfp2_to_f2(hp[((long)c << 4) + q]);   // self
        int e = e0;
        for (; e + 7 < e1; e += 8) {
            int r0 = srcs[e],     r1 = srcs[e + 1], r2 = srcs[e + 2], r3 = srcs[e + 3];
            int r4 = srcs[e + 4], r5 = srcs[e + 5], r6 = srcs[e + 6], r7 = srcs[e + 7];
            float2 v0 = bfp2_to_f2(hp[((long)r0 << 4) + q]);
            float2 v1 = bfp2_to_f2(hp[((long)r1 << 4) + q]);
            float2 v2 = bfp2_to_f2(hp[((long)r2 << 4) + q]);
            float2 v3 = bfp2_to_f2(hp[((long)r3 << 4) + q]);
            float2 v4 = bfp2_to_f2(hp[((long)r4 << 4) + q]);
            float2 v5 = bfp2_to_f2(hp[((long)r5 << 4) + q]);
            float2 v6 = bfp2_to_f2(hp[((long)r6 << 4) + q]);
            float2 v7 = bfp2_to_f2(hp[((long)r7 << 4) + q]);
            acc.x += (v0.x + v1.x) + (v2.x + v3.x) + (v4.x + v5.x) + (v6.x + v7.x);
            acc.y += (v0.y + v1.y) + (v2.y + v3.y) + (v4.y + v5.y) + (v6.y + v7.y);
        }
        for (; e + 3 < e1; e += 4) {
            int r0 = srcs[e], r1 = srcs[e + 1], r2 = srcs[e + 2], r3 = srcs[e + 3];
            float2 v0 = bfp2_to_f2(hp[((long)r0 << 4) + q]);
            float2 v1 = bfp2_to_f2(hp[((long)r1 << 4) + q]);
            float2 v2 = bfp2_to_f2(hp[((long)r2 << 4) + q]);
            float2 v3 = bfp2_to_f2(hp[((long)r3 << 4) + q]);
            acc.x += (v0.x + v1.x) + (v2.x + v3.x);
            acc.y += (v0.y + v1.y) + (v2.y + v3.y);
        }
        for (; e < e1; ++e) {
            int r = srcs[e];
            float2 v = bfp2_to_f2(hp[((long)r << 4) + q]);
            acc.x += v.x; acc.y += v.y;
        }
        float b0 = bg[2 * q], b1v = bg[2 * q + 1];
        float t0 = acc.x * dc + b0, t1 = acc.y * dc + b1v;
        float2 res;
        if (mode == 0) {
            res.x = (t0 >= 0.f) ? t0 : SLOPE * t0;
            res.y = (t1 >= 0.f) ? t1 : SLOPE * t1;
        } else {
            res.x = (t0 >= 0.f) ? 2.f * t0 : (1.f + SLOPE) * t0;
            res.y = (t1 >= 0.f) ? 2.f * t1 : (1.f + SLOPE) * t1;
        }
        *(float2*)&hrow[n][2 * q] = res;
    }
    __syncthreads();
    // phase 2: per-node matmul (32 x 32), 8 threads/node, 4 outputs each
    int n2 = t >> 3;
    int q2 = t & 7;
    if (n2 < NPB) {
        int c2 = blockIdx.x * NPB + n2;
        if (c2 < N) {
            const float* wp = W + 4 * q2;
            float4 acc = make_float4(0.f, 0.f, 0.f, 0.f);
#pragma unroll
            for (int kk = 0; kk < DG / 4; ++kk) {
                float4 a = *(const float4*)&hrow[n2][4 * kk];
                float4 w0 = *(const float4*)(wp + (long)(4 * kk)     * 32);
                float4 w1 = *(const float4*)(wp + (long)(4 * kk + 1) * 32);
                float4 w2 = *(const float4*)(wp + (long)(4 * kk + 2) * 32);
                float4 w3 = *(const float4*)(wp + (long)(4 * kk + 3) * 32);
                acc.x += a.x * w0.x + a.y * w1.x + a.z * w2.x + a.w * w3.x;
                acc.y += a.x * w0.y + a.y * w1.y + a.z * w2.y + a.w * w3.y;
                acc.z += a.x * w0.z + a.y * w1.z + a.z * w2.z + a.w * w3.z;
                acc.w += a.x * w0.w + a.y * w1.w + a.z * w2.w + a.w * w3.w;
            }
            float di = dinv[c2];
            acc.x *= di; acc.y *= di; acc.z *= di; acc.w *= di;
            *(ushort4*)(hwsOut + (long)c2 * 32 + 4 * q2) = f2bf4(acc);
        }
    }
}

// fused last (R25): gather bf16 32-dim QG=16 (mode1) -> act -> dot W5 -> f32 hws
__global__ void k_fused_last_w(const int* __restrict__ off,
                               const unsigned short* __restrict__ srcs,
                               const float* __restrict__ dinv,
                               const unsigned short* __restrict__ hin,
                               const float* __restrict__ bg,
                               const float* __restrict__ W5,
                               float* __restrict__ hwsOut, int N) {
    constexpr int DG = 32, QG = 16, NPB = 16;
    __shared__ float hrow[NPB][DG + 4];
    int t = threadIdx.x;
    int n = t / QG, q = t % QG;
    int c = blockIdx.x * NPB + n;
    const unsigned int* hp = (const unsigned int*)hin;   // row stride 16 u32
    if (c < N) {
        int e0 = off[c], e1 = off[c + 1];
        float dc = dinv[c];
        float2 acc = bfp2_to_f2(hp[((long)c << 4) + q]);
        int e = e0;
        for (; e + 7 < e1; e += 8) {
            int r0 = srcs[e],     r1 = srcs[e + 1], r2 = srcs[e + 2], r3 = srcs[e + 3];
            int r4 = srcs[e + 4], r5 = srcs[e + 5], r6 = srcs[e + 6], r7 = srcs[e + 7];
            float2 v0 = bfp2_to_f2(hp[((long)r0 << 4) + q]);
            float2 v1 = bfp2_to_f2(hp[((long)r1 << 4) + q]);
            float2 v2 = bfp2_to_f2(hp[((long)r2 << 4) + q]);
            float2 v3 = bfp2_to_f2(hp[((long)r3 << 4) + q]);
            float2 v4 = bfp2_to_f2(hp[((long)r4 << 4) + q]);
            float2 v5 = bfp2_to_f2(hp[((long)r5 << 4) + q]);
            float2 v6 = bfp2_to_f2(hp[((long)r6 << 4) + q]);
            float2 v7 = bfp2_to_f2(hp[((long)r7 << 4) + q]);
            acc.x += (v0.x + v1.x) + (v2.x + v3.x) + (v4.x + v5.x) + (v6.x + v7.x);
            acc.y += (v0.y + v1.y) + (v2.y + v3.y) + (v4.y + v5.y) + (v6.y + v7.y);
        }
        for (; e + 3 < e1; e += 4) {
            int r0 = srcs[e], r1 = srcs[e + 1], r2 = srcs[e + 2], r3 = srcs[e + 3];
            float2 v0 = bfp2_to_f2(hp[((long)r0 << 4) + q]);
            float2 v1 = bfp2_to_f2(hp[((long)r1 << 4) + q]);
            float2 v2 = bfp2_to_f2(hp[((long)r2 << 4) + q]);
            float2 v3 = bfp2_to_f2(hp[((long)r3 << 4) + q]);
            acc.x += (v0.x + v1.x) + (v2.x + v3.x);
            acc.y += (v0.y + v1.y) + (v2.y + v3.y);
        }
        for (; e < e1; ++e) {
            int r = srcs[e];
            float2 v = bfp2_to_f2(hp[((long)r << 4) + q]);
            acc.x += v.x; acc.y += v.y;
        }
        float b0 = bg[2 * q], b1v = bg[2 * q + 1];
        float t0 = acc.x * dc + b0, t1 = acc.y * dc + b1v;
        float2 res;   // mode 1
        res.x = (t0 >= 0.f) ? 2.f * t0 : (1.f + SLOPE) * t0;
        res.y = (t1 >= 0.f) ? 2.f * t1 : (1.f + SLOPE) * t1;
        *(float2*)&hrow[n][2 * q] = res;
    }
    __syncthreads();
    if (t < NPB) {
        int c2 = blockIdx.x * NPB + t;
        if (c2 < N) {
            float acc = 0.f;
#pragma unroll
            for (int kk = 0; kk < 8; ++kk) {
                float4 a = *(const float4*)&hrow[t][4 * kk];
                acc += a.x * W5[4 * kk] + a.y * W5[4 * kk + 1]
                     + a.z * W5[4 * kk + 2] + a.w * W5[4 * kk + 3];
            }
            hwsOut[c2] = acc * dinv[c2];
        }
    }
}

// ---------------- tail: final gather (V in LDS) + fc1a partials fused ---------------
__global__ void k_tail(const int* __restrict__ off,
                       const unsigned short* __restrict__ srcs,
                       const float* __restrict__ dinv, const float* __restrict__ hws,
                       const float* __restrict__ b5,
                       const float* __restrict__ Wf1, double* __restrict__ part,
                       int N, int chunk) {
    __shared__ float Vl[96];
    int bl = blockIdx.x, t = threadIdx.x;
    int i0 = bl * chunk;
    int i1 = min(i0 + chunk, N);
    int cnt = i1 - i0;
    if (t < cnt) {
        int c = i0 + t;
        int e0 = off[c], e1 = off[c + 1];
        float acc = hws[c];
        float a1 = 0.f, a2 = 0.f, a3 = 0.f;
        int e = e0;
        for (; e + 3 < e1; e += 4) {
            acc += hws[srcs[e]];
            a1  += hws[srcs[e + 1]];
            a2  += hws[srcs[e + 2]];
            a3  += hws[srcs[e + 3]];
        }
        for (; e < e1; ++e) acc += hws[srcs[e]];
        float tt = (acc + a1 + a2 + a3) * dinv[c] + b5[0];
        Vl[t] = (tt >= 0.f) ? tt : SLOPE * tt;
    }
    __syncthreads();
    int j = t;   // 128 threads, one per output column
    double a0 = 0.0, a1 = 0.0, a2 = 0.0, a3 = 0.0;
    int i = 0;
    for (; i + 3 < cnt; i += 4) {
        a0 += (double)Vl[i]     * (double)Wf1[(long)(i0 + i)     * 128 + j];
        a1 += (double)Vl[i + 1] * (double)Wf1[(long)(i0 + i + 1) * 128 + j];
        a2 += (double)Vl[i + 2] * (double)Wf1[(long)(i0 + i + 2) * 128 + j];
        a3 += (double)Vl[i + 3] * (double)Wf1[(long)(i0 + i + 3) * 128 + j];
    }
    for (; i < cnt; ++i)
        a0 += (double)Vl[i] * (double)Wf1[(long)(i0 + i) * 128 + j];
    part[bl * 128 + j] = (a0 + a1) + (a2 + a3);
}

__global__ void k_fc1b(const double* __restrict__ part, const float* __restrict__ bf1,
                       float* __restrict__ o1) {
    __shared__ double red[256];
    int j = blockIdx.x;
    int t = threadIdx.x;
    double a = part[t * 128 + j] + part[(t + 256) * 128 + j];
    red[t] = a;
    __syncthreads();
    for (int s = 128; s > 0; s >>= 1) {
        if (t < s) red[t] += red[t + s];
        __syncthreads();
    }
    if (t == 0) {
        double v = red[0] + (double)bf1[j];
        o1[j] = (float)((v > 0.0) ? v : 0.0);
    }
}

__global__ void k_fc2(const float* __restrict__ o1, const float* __restrict__ Wf2,
                      const float* __restrict__ bf2, float* __restrict__ out) {
    __shared__ double red[128];
    int j = blockIdx.x;
    int k = threadIdx.x;
    red[k] = (double)o1[k] * (double)Wf2[(long)k * 128 + j];
    __syncthreads();
    for (int s = 64; s > 0; s >>= 1) {
        if (k < s) red[k] += red[k + s];
        __syncthreads();
    }
    if (k == 0) {
        double u = red[0] + (double)bf2[j];
        out[j] = (float)((u > 0.0) ? u : 0.0);
    }
}

extern "C" void kernel_launch(void* const* d_in, const int* in_sizes, int n_in,
                              void* d_out, int out_size, void* d_ws, size_t ws_size,
                              hipStream_t stream) {
    const float* x   = (const float*)d_in[0];
    const int*   ei  = (const int*)d_in[1];
    const float* emb = (const float*)d_in[2];
    const float* W1  = (const float*)d_in[3];
    const float* b1  = (const float*)d_in[4];
    const float* W2  = (const float*)d_in[5];
    const float* b2  = (const float*)d_in[6];
    const float* W3  = (const float*)d_in[7];
    const float* b3  = (const float*)d_in[8];
    const float* W4  = (const float*)d_in[9];
    const float* b4  = (const float*)d_in[10];
    const float* W5  = (const float*)d_in[11];
    const float* b5  = (const float*)d_in[12];
    const float* Wf1 = (const float*)d_in[13];
    const float* bf1 = (const float*)d_in[14];
    const float* Wf2 = (const float*)d_in[15];
    const float* bf2 = (const float*)d_in[16];

    const int N = in_sizes[0] / 5;
    const int E = in_sizes[1] / 2;
    const int* row = ei;
    const int* col = ei + E;
    const int S = (N + NB - 1) / NB;           // bucket width (150 for N=38333, NB=256)
    const int Np = N + 4;                       // padded rows for 4-node tiles

    // --- workspace carving ---
    char* ws = (char*)d_ws;
    size_t off_b = 0;
    auto alloc = [&](size_t bytes) -> void* {
        void* p = ws + off_b;
        off_b += (bytes + 255) & ~(size_t)255;
        return p;
    };
    int*   offcsr = (int*)alloc((size_t)(N + 1) * sizeof(int));
    int*   bhist  = (int*)alloc((size_t)HBLK * NB * sizeof(int));
    int*   gcur   = (int*)alloc((size_t)NB * sizeof(int));
    int*   gstart = (int*)alloc((size_t)(NB + 1) * sizeof(int));
    unsigned short* srcs = (unsigned short*)alloc((size_t)E * sizeof(unsigned short));
    unsigned int* ebuf = (unsigned int*)alloc((size_t)E * sizeof(unsigned int));
    float* dinv   = (float*)alloc((size_t)Np * sizeof(float));
    float* W1p    = (float*)alloc((size_t)128 * 64 * sizeof(float));
    unsigned short* H0   = (unsigned short*)alloc((size_t)Np * 128 * sizeof(unsigned short));
    unsigned char*  X64f8 = (unsigned char*)alloc((size_t)Np * 64 * sizeof(unsigned char));
    unsigned short* X32a = (unsigned short*)alloc((size_t)Np * 32 * sizeof(unsigned short));
    unsigned short* X32b = (unsigned short*)alloc((size_t)Np * 32 * sizeof(unsigned short));
    unsigned short* X32c = (unsigned short*)alloc((size_t)Np * 32 * sizeof(unsigned short));
    float* HWSf   = (float*)alloc((size_t)Np * sizeof(float));
    double* part  = (double*)alloc((size_t)FC1_BLOCKS * 128 * sizeof(double));
    float* O1     = (float*)alloc(128 * sizeof(float));

    // --- front: merged (bucket-hist -> bhist | h0 bf16 x4 | W1pad) ---
    int h0Blocks  = cdiv_l((long)N * 32, 256);
    int padBlocks = cdiv_l(128 * 64, 256);
    k_front<<<HBLK + h0Blocks + padBlocks, 256, 0, stream>>>(
        col, bhist, E, S, x, emb, H0, N, W1, W1p, h0Blocks);

    // --- CSR build: bscan -> bucket -> in-bucket counting sort ---
    k_bscan<<<1, 1024, 0, stream>>>(bhist, gcur, gstart);
    k_bucket<<<cdiv_l(E, BCHUNK), 256, 0, stream>>>(row, col, gcur, ebuf, E, S);
    k_sortb<<<NB, 1024, 0, stream>>>(ebuf, gstart, offcsr, dinv, srcs, N, S, E);

    // --- GCN: L1 dense (fp8 out), then fused gather+matmul chain ---
    {
        int G = (N + 3) / 4;
        k_hw_rb8<<<cdiv_l((long)G * 16, 256), 256, 0, stream>>>(
            H0, 128, W1p, dinv, X64f8, N);
    }
    k_fused64_fp8<<<cdiv_l(N, 16), 256, 0, stream>>>(
        offcsr, srcs, dinv, X64f8, b1, W2, X32a, N);
    k_fused32w<<<cdiv_l(N, 16), 256, 0, stream>>>(
        offcsr, srcs, dinv, X32a, b2, 0, W3, X32b, N);
    k_fused32w<<<cdiv_l(N, 16), 256, 0, stream>>>(
        offcsr, srcs, dinv, X32b, b3, 1, W4, X32c, N);
    k_fused_last_w<<<cdiv_l(N, 16), 256, 0, stream>>>(
        offcsr, srcs, dinv, X32c, b4, W5, HWSf, N);

    // --- tail: final gather + fc1a fused; then fc1b, fc2 ---
    int chunk = (N + FC1_BLOCKS - 1) / FC1_BLOCKS;   // 75 (< 96 LDS cap)
    k_tail<<<FC1_BLOCKS, 128, 0, stream>>>(
        offcsr, srcs, dinv, HWSf, b5, Wf1, part, N, chunk);
    k_fc1b<<<128, 256, 0, stream>>>(part, bf1, O1);
    k_fc2<<<128, 128, 0, stream>>>(O1, Wf2, bf2, (float*)d_out);
}